// Round 23
// baseline (850.723 us; speedup 1.0000x reference)
//
#include <hip/hip_runtime.h>
#include <math.h>

#define T_TOK 8192
#define DDIM  1024
#define FDIM  4096
#define NEXP  8
#define MT256 72                  // max 256-row tiles (8 experts x 9)
#define NSLOT (2 * T_TOK)
#define NG1   (16 * MT256)        // 1152 = 8 XCDs x (9 t x 16 n)
#define NG2   (8 * MT256)         // 576  = 8 XCDs x (9 t x 8 combos)

typedef __attribute__((ext_vector_type(8))) short short8;
typedef __attribute__((ext_vector_type(4))) float f32x4;
typedef unsigned short u16;
typedef unsigned int   u32;

typedef const __attribute__((address_space(1))) u32* gp_t;
typedef       __attribute__((address_space(3))) u32* lp_t;

__device__ __forceinline__ void gload16(const void* g, void* l) {
  __builtin_amdgcn_global_load_lds((gp_t)g, (lp_t)l, 16, 0, 0);
}

#define VM2 asm volatile("s_waitcnt vmcnt(2)" ::: "memory")
#define VM0 asm volatile("s_waitcnt vmcnt(0)" ::: "memory")
#define SBAR __builtin_amdgcn_s_barrier()
#define SCHED0 __builtin_amdgcn_sched_barrier(0)

__device__ __forceinline__ u16 f2bf(float f) {
  u32 u = __float_as_uint(f);
  u = u + 0x7FFFu + ((u >> 16) & 1u);
  return (u16)(u >> 16);
}

__device__ __forceinline__ int imin(int a, int b) { return a < b ? a : b; }

// fast gelu (tanh form); |err| vs exact-erf gelu ~1e-3 << 0.0398 threshold
__device__ __forceinline__ float gelu_fast(float v) {
  float u = 0.7978845608f * (v + 0.044715f * v * v * v);
  float t2 = __expf(2.f * u);
  float th = 1.f - 2.f / (t2 + 1.f);
  return 0.5f * v * (1.f + th);
}

// bijective XCD chunking (m204): XCD k owns logical ids [k*q, (k+1)*q)
__device__ __forceinline__ int xcd_swz(int orig, int nwg) {
  int xcd = orig & 7;
  int q = nwg >> 3, r = nwg & 7;
  int base = (xcd < r) ? xcd * (q + 1) : r * (q + 1) + (xcd - r) * q;
  return base + (orig >> 3);
}

// ---------------- wtrans: no-LDS transpose, f32 [Min][Nin] -> bf16 [Nin][Min]
// Lane l owns in-column n0+l. 8 scalar f32 loads per group (each instr =
// 64 lanes x 4B consecutive = 256B coalesced), pack short8, ONE 16B
// contiguous store. Block's 4 waves tile adjacent 8-row groups -> their
// 16B stores fill the same 64B lines (L2 merge). No LDS, no barrier.
// blocks 0..4095: W2 (512/expert, 32tm x 16tn); 4096..8191: W1 (8tm x 64tn).
__global__ __launch_bounds__(256) void wtrans_kernel(
    const float* __restrict__ w1, u16* __restrict__ w1t,
    const float* __restrict__ w2, u16* __restrict__ w2t)
{
  const int b = blockIdx.x;
  const float* in; u16* out; int Min, Nin, m0, n0;
  if (b < 4096) {
    int e = b >> 9, rem = b & 511;
    int tm = rem >> 4, tn = rem & 15;   // 32 x 16
    in = w2 + (size_t)e * FDIM * DDIM; out = w2t + (size_t)e * FDIM * DDIM;
    Min = FDIM; Nin = DDIM; m0 = tm * 128; n0 = tn * 64;
  } else {
    int bb = b - 4096;
    int e = bb >> 9, rem = bb & 511;
    int tm = rem >> 6, tn = rem & 63;   // 8 x 64
    in = w1 + (size_t)e * DDIM * FDIM; out = w1t + (size_t)e * DDIM * FDIM;
    Min = DDIM; Nin = FDIM; m0 = tm * 128; n0 = tn * 64;
  }
  const int w = threadIdx.x >> 6, l = threadIdx.x & 63;
  const int c = n0 + l;                  // in-column == out-row
  #pragma unroll 1
  for (int it = 0; it < 4; it++) {
    int r0 = m0 + it * 32 + w * 8;
    short8 o;
    #pragma unroll
    for (int j = 0; j < 8; j++)
      o[j] = (short)f2bf(in[(size_t)(r0 + j) * Nin + c]);
    *(short8*)(out + (size_t)c * Min + r0) = o;
  }
}

// ---------------- router (+ x->bf16): one wave per token; gw staged in LDS --
__global__ __launch_bounds__(256) void router_kernel(
    const float* __restrict__ x, const float* __restrict__ gw,
    const float* __restrict__ gb, u16* __restrict__ xb,
    int* __restrict__ counts, int* __restrict__ sel, float* __restrict__ wts)
{
  __shared__ __align__(16) float gwT[8 * 1028];
  {
    const int tid = threadIdx.x;          // stage gw [1024][8] -> gwT[e][d]
    #pragma unroll
    for (int q = 0; q < 4; q++) {
      int d = q * 256 + tid;
      float4 a = *(const float4*)(gw + (size_t)d * NEXP);
      float4 cc = *(const float4*)(gw + (size_t)d * NEXP + 4);
      gwT[0 * 1028 + d] = a.x; gwT[1 * 1028 + d] = a.y;
      gwT[2 * 1028 + d] = a.z; gwT[3 * 1028 + d] = a.w;
      gwT[4 * 1028 + d] = cc.x; gwT[5 * 1028 + d] = cc.y;
      gwT[6 * 1028 + d] = cc.z; gwT[7 * 1028 + d] = cc.w;
    }
  }
  __syncthreads();
  const int t    = blockIdx.x * 4 + (threadIdx.x >> 6);
  const int lane = threadIdx.x & 63;
  const float* xr = x + (size_t)t * DDIM;
  u16* xbr = xb + (size_t)t * DDIM;
  float lg[NEXP];
  #pragma unroll
  for (int e = 0; e < NEXP; e++) lg[e] = 0.f;
  #pragma unroll
  for (int i = 0; i < 4; i++) {
    int d0 = i * 256 + lane * 4;
    float4 v = *(const float4*)(xr + d0);
    ushort4 o;
    o.x = f2bf(v.x); o.y = f2bf(v.y); o.z = f2bf(v.z); o.w = f2bf(v.w);
    *(ushort4*)(xbr + d0) = o;
    #pragma unroll
    for (int e = 0; e < NEXP; e++) {
      float4 g4 = *(const float4*)&gwT[e * 1028 + d0];
      lg[e] += v.x * g4.x + v.y * g4.y + v.z * g4.z + v.w * g4.w;
    }
  }
  #pragma unroll
  for (int off = 32; off > 0; off >>= 1) {
    #pragma unroll
    for (int e = 0; e < NEXP; e++) lg[e] += __shfl_down(lg[e], off);
  }
  if (lane == 0) {
    float v0 = -1e30f, v1 = -1e30f; int s0 = 0, s1 = 0;
    #pragma unroll
    for (int e = 0; e < NEXP; e++) {
      float v = lg[e] + gb[e];
      if (v > v0) { v1 = v0; s1 = s0; v0 = v; s0 = e; }
      else if (v > v1) { v1 = v; s1 = e; }
    }
    float a  = expf(v1 - v0);
    float w0 = 1.f / (1.f + a);
    sel[t * 2] = s0; sel[t * 2 + 1] = s1;
    wts[t * 2] = w0; wts[t * 2 + 1] = 1.f - w0;
    atomicAdd(&counts[s0], 1); atomicAdd(&counts[s1], 1);
  }
}

// ---------------- scan + tile map (256-row tiles) + slot assignment ----------
__global__ __launch_bounds__(1024) void scan_assign_kernel(
    const int* __restrict__ counts, const int* __restrict__ sel,
    const float* __restrict__ wts,
    int* __restrict__ offsets, int* __restrict__ map_e, int* __restrict__ map_r,
    int* __restrict__ nT, int* __restrict__ stok, float* __restrict__ swgt)
{
  __shared__ int spos[NEXP];
  if (threadIdx.x == 0) {
    int run = 0, nt = 0;
    for (int e = 0; e < NEXP; e++) {
      offsets[e] = run; spos[e] = run;
      int c = counts[e];
      int ntile = (c + 255) >> 8;
      for (int i = 0; i < ntile; i++) { map_e[nt] = e; map_r[nt] = i * 256; nt++; }
      run += c;
    }
    nT[0] = nt;
  }
  __syncthreads();
  for (int t = threadIdx.x; t < T_TOK; t += 1024) {
    #pragma unroll
    for (int k = 0; k < 2; k++) {
      int e = sel[t * 2 + k];
      int p = atomicAdd(&spos[e], 1);
      stok[p] = t; swgt[p] = wts[t * 2 + k];
    }
  }
}

// ---------------- grouped GEMM1: H = gelu(X[stok]@W1 + b1) ----------------
// R15-proven core: 256x256, BK=32, 1024 thr (16 waves, 4Mx4N), ring-3 96KB,
// counted vmcnt(2) lead-2. A staged via per-lane slot_token gather from xb.
__global__ __launch_bounds__(1024, 4) void gemm1_kernel(
    const u16* __restrict__ xb, const int* __restrict__ slot_token,
    const u16* __restrict__ W1T, const float* __restrict__ B1,
    const int* __restrict__ counts, const int* __restrict__ offsets,
    const int* __restrict__ map_e, const int* __restrict__ map_r,
    const int* __restrict__ nT, u16* __restrict__ H)
{
  __shared__ __align__(16) char lds[3 * 32768]; // slot: [A 16KB | B 16KB]
  const int L     = xcd_swz(blockIdx.x, NG1);
  const int xg    = L / 144;               // XCD 0..7
  const int local = L - xg * 144;
  const int tl    = local >> 4;            // 0..8 (9 t-tiles per XCD)
  const int n_idx = local & 15;            // n innermost: A reuse in L2
  const int t_idx = xg * 9 + tl;
  if (t_idx >= nT[0]) return;
  const int e    = map_e[t_idx];
  const int row0 = map_r[t_idx];
  const int cnt  = counts[e];
  const int off  = offsets[e];
  const int n0   = n_idx * 256;

  const int tid = threadIdx.x, wave = tid >> 6, lane = tid & 63;
  const int lr = lane & 15, lq = lane >> 4;
  const int wr = wave >> 2, wc = wave & 3;  // 4M x 4N
  const int l2 = lane >> 2, lb = (lane & 3) * 16;

  const int R = wave * 16 + l2;
  int tok = slot_token[imin(off + row0 + R, NSLOT - 1)];
  if ((u32)tok >= T_TOK) tok = 0;
  const char* gA = (const char*)xb + (size_t)tok * 2048 + lb;
  const char* gB = (const char*)W1T + (size_t)(e * FDIM + n0 + R) * 2048 + lb;

  auto stage = [&](int slot, int k0) {
    char* base = lds + slot * 32768;
    gload16(gA + k0, base + wave * 1024 + lane * 16);
    gload16(gB + k0, base + 16384 + wave * 1024 + lane * 16);
  };

  f32x4 acc[4][4] = {};
  auto compute = [&](int slot) {
    const u16* As = (const u16*)(lds + slot * 32768);
    const u16* Bs = (const u16*)(lds + slot * 32768 + 16384);
    short8 a[4], bf[4];
    #pragma unroll
    for (int m = 0; m < 4; m++)
      a[m] = *(const short8*)&As[(wr * 64 + m * 16 + lr) * 32 + lq * 8];
    #pragma unroll
    for (int n = 0; n < 4; n++)
      bf[n] = *(const short8*)&Bs[(wc * 64 + n * 16 + lr) * 32 + lq * 8];
    #pragma unroll
    for (int m = 0; m < 4; m++)
      #pragma unroll
      for (int n = 0; n < 4; n++)
        acc[m][n] = __builtin_amdgcn_mfma_f32_16x16x32_bf16(a[m], bf[n], acc[m][n], 0, 0, 0);
  };

  // NT = 32 K-steps (K=1024, BK=32; 64B per step). Ring-3, lead-2.
  stage(0, 0); stage(1, 64);
  VM2; SCHED0; SBAR; SCHED0;
  #pragma unroll 1
  for (int t = 0; t < 32; t++) {
    if (t + 2 < 32) stage((t + 2) % 3, (t + 2) * 64);
    compute(t % 3);
    SCHED0;
    if (t + 2 < 32)       { VM2; }
    else if (t + 2 == 32) { VM0; }
    SCHED0; SBAR; SCHED0;
  }

  // epilogue: gelu + bias + bf16 store
  #pragma unroll
  for (int nn = 0; nn < 4; nn++) {
    int col = n0 + wc * 64 + nn * 16 + lr;
    float b1v = B1[e * FDIM + col];
    #pragma unroll
    for (int m = 0; m < 4; m++) {
      int rbase = wr * 64 + m * 16 + lq * 4;
      #pragma unroll
      for (int j = 0; j < 4; j++) {
        int r = rbase + j;
        if (row0 + r < cnt) {
          float v = acc[m][nn][j] + b1v;
          H[(size_t)(off + row0 + r) * FDIM + col] = f2bf(gelu_fast(v));
        }
      }
    }
  }
}

// ---------------- grouped GEMM2 + fused combine ----------------
// R15-proven core; split-K=2 (NT=64 each). t-sliced decode: H rows re-read
// on the XCD that wrote them. out[tok] += wgt*(H@W2 + b2) via f32 atomics.
__global__ __launch_bounds__(1024, 4) void gemm2_kernel(
    const u16* __restrict__ H, const u16* __restrict__ W2T,
    const float* __restrict__ B2,
    const int* __restrict__ counts, const int* __restrict__ offsets,
    const int* __restrict__ slot_token, const float* __restrict__ slot_weight,
    const int* __restrict__ map_e, const int* __restrict__ map_r,
    const int* __restrict__ nT, float* __restrict__ out)
{
  __shared__ __align__(16) char lds[3 * 32768];
  const int L     = xcd_swz(blockIdx.x, NG2);
  const int xg    = L / 72;
  const int local = L - xg * 72;
  const int tl    = local >> 3;            // 0..8
  const int combo = local & 7;             // combo innermost: A reuse in L2
  const int sp    = combo >> 2;            // split-K half
  const int n_idx = combo & 3;             // 4 n-panels of 256
  const int t_idx = xg * 9 + tl;
  if (t_idx >= nT[0]) return;
  const int e    = map_e[t_idx];
  const int row0 = map_r[t_idx];
  const int cnt  = counts[e];
  const int off  = offsets[e];
  const int n0   = n_idx * 256;
  const int kbase = sp * 4096;             // bytes: elems [sp*2048, +2048)

  const int tid = threadIdx.x, wave = tid >> 6, lane = tid & 63;
  const int lr = lane & 15, lq = lane >> 4;
  const int wr = wave >> 2, wc = wave & 3;  // 4M x 4N
  const int l2 = lane >> 2, lb = (lane & 3) * 16;

  const int R = wave * 16 + l2;
  int aidx = imin(off + row0 + R, NSLOT - 1);
  const char* gA = (const char*)H + (size_t)aidx * 8192 + kbase + lb;
  const char* gB = (const char*)W2T + (size_t)(e * DDIM + n0 + R) * 8192 + kbase + lb;

  auto stage = [&](int slot, int k0) {
    char* base = lds + slot * 32768;
    gload16(gA + k0, base + wave * 1024 + lane * 16);
    gload16(gB + k0, base + 16384 + wave * 1024 + lane * 16);
  };

  f32x4 acc[4][4] = {};
  auto compute = [&](int slot) {
    const u16* As = (const u16*)(lds + slot * 32768);
    const u16* Bs = (const u16*)(lds + slot * 32768 + 16384);
    short8 a[4], bf[4];
    #pragma unroll
    for (int m = 0; m < 4; m++)
      a[m] = *(const short8*)&As[(wr * 64 + m * 16 + lr) * 32 + lq * 8];
    #pragma unroll
    for (int n = 0; n < 4; n++)
      bf[n] = *(const short8*)&Bs[(wc * 64 + n * 16 + lr) * 32 + lq * 8];
    #pragma unroll
    for (int m = 0; m < 4; m++)
      #pragma unroll
      for (int n = 0; n < 4; n++)
        acc[m][n] = __builtin_amdgcn_mfma_f32_16x16x32_bf16(a[m], bf[n], acc[m][n], 0, 0, 0);
  };

  // NT = 64 K-steps (split K=2048, BK=32). Ring-3, lead-2.
  stage(0, 0); stage(1, 64);
  VM2; SCHED0; SBAR; SCHED0;
  #pragma unroll 1
  for (int t = 0; t < 64; t++) {
    if (t + 2 < 64) stage((t + 2) % 3, (t + 2) * 64);
    compute(t % 3);
    SCHED0;
    if (t + 2 < 64)       { VM2; }
    else if (t + 2 == 64) { VM0; }
    SCHED0; SBAR; SCHED0;
  }

  #pragma unroll
  for (int m = 0; m < 4; m++) {
    int rbase = wr * 64 + m * 16 + lq * 4;
    #pragma unroll
    for (int j = 0; j < 4; j++) {
      int r = rbase + j;
      if (row0 + r >= cnt) continue;
      int s = off + row0 + r;
      int tok = slot_token[s];
      float wgt = slot_weight[s];
      #pragma unroll
      for (int n = 0; n < 4; n++) {
        int col = n0 + wc * 64 + n * 16 + lr;
        float v = acc[m][n][j];
        if (sp == 0) v += B2[e * DDIM + col];
        atomicAdd(&out[(size_t)tok * DDIM + col], wgt * v);
      }
    }
  }
}

extern "C" void kernel_launch(void* const* d_in, const int* in_sizes, int n_in,
                              void* d_out, int out_size, void* d_ws, size_t ws_size,
                              hipStream_t stream)
{
  (void)in_sizes; (void)n_in; (void)ws_size;
  const float* x  = (const float*)d_in[0];
  const float* gw = (const float*)d_in[1];
  const float* gb = (const float*)d_in[2];
  const float* w1 = (const float*)d_in[3];
  const float* b1 = (const float*)d_in[4];
  const float* w2 = (const float*)d_in[5];
  const float* b2 = (const float*)d_in[6];

  char* ws = (char*)d_ws;
  int*   counts = (int*)(ws + 0);
  int*   offp   = (int*)(ws + 64);
  int*   nT     = (int*)(ws + 128);
  int*   map_e  = (int*)(ws + 256);
  int*   map_r  = (int*)(ws + 1024);

  size_t p = 2048;
  int*   sel   = (int*)(ws + p);   p += (size_t)T_TOK * 2 * 4;
  float* wts   = (float*)(ws + p); p += (size_t)T_TOK * 2 * 4;
  int*   stok  = (int*)(ws + p);   p += (size_t)NSLOT * 4;
  float* swgt  = (float*)(ws + p); p += (size_t)NSLOT * 4;
  p = (p + 1048575) & ~(size_t)1048575;
  u16*   xb    = (u16*)(ws + p);   p += (size_t)T_TOK * DDIM * 2;
  u16*   w1t   = (u16*)(ws + p);   p += (size_t)NEXP * DDIM * FDIM * 2;
  u16*   w2t   = (u16*)(ws + p);   p += (size_t)NEXP * DDIM * FDIM * 2;
  u16*   Hbuf  = (u16*)(ws + p);   // (NSLOT + 256) rows x FDIM bf16

  hipMemsetAsync(ws, 0, 256, stream);
  hipMemsetAsync(d_out, 0, (size_t)out_size * sizeof(float), stream);
  router_kernel<<<T_TOK / 4, 256, 0, stream>>>(x, gw, gb, xb, counts, sel, wts);
  wtrans_kernel<<<8192, 256, 0, stream>>>(w1, w1t, w2, w2t);
  scan_assign_kernel<<<1, 1024, 0, stream>>>(counts, sel, wts, offp, map_e, map_r, nT, stok, swgt);
  gemm1_kernel<<<NG1, 1024, 0, stream>>>(
      xb, stok, w1t, b1, counts, offp, map_e, map_r, nT, Hbuf);
  gemm2_kernel<<<NG2, 1024, 0, stream>>>(
      Hbuf, w2t, b2, counts, offp, stok, swgt, map_e, map_r, nT, (float*)d_out);
}

// Round 24
// 749.344 us; speedup vs baseline: 1.1353x; 1.1353x over previous
//
#include <hip/hip_runtime.h>
#include <math.h>

#define T_TOK 8192
#define DDIM  1024
#define FDIM  4096
#define NEXP  8
#define MT256 72                  // max 256-row tiles (8 experts x 9)
#define NSLOT (2 * T_TOK)
#define NG1   (16 * MT256)        // 1152 = 8 XCDs x (9 t x 16 n)
#define NG2   (8 * MT256)         // 576  = 8 XCDs x (9 t x 8 combos)
#define NW2T  2048                // W2 transpose blocks appended to gemm1

typedef __attribute__((ext_vector_type(8))) short short8;
typedef __attribute__((ext_vector_type(4))) float f32x4;
typedef __attribute__((ext_vector_type(4))) unsigned int u32x4;
typedef unsigned short u16;
typedef unsigned int   u32;

typedef const __attribute__((address_space(1))) u32* gp_t;
typedef       __attribute__((address_space(3))) u32* lp_t;

__device__ __forceinline__ void gload16(const void* g, void* l) {
  __builtin_amdgcn_global_load_lds((gp_t)g, (lp_t)l, 16, 0, 0);
}

#define VM2 asm volatile("s_waitcnt vmcnt(2)" ::: "memory")
#define VM0 asm volatile("s_waitcnt vmcnt(0)" ::: "memory")
#define SBAR __builtin_amdgcn_s_barrier()
#define SCHED0 __builtin_amdgcn_sched_barrier(0)

__device__ __forceinline__ u16 f2bf(float f) {
  u32 u = __float_as_uint(f);
  u = u + 0x7FFFu + ((u >> 16) & 1u);
  return (u16)(u >> 16);
}

__device__ __forceinline__ int imin(int a, int b) { return a < b ? a : b; }

// fast gelu (tanh form); |err| vs exact-erf gelu ~1e-3 << 0.0398 threshold
__device__ __forceinline__ float gelu_fast(float v) {
  float u = 0.7978845608f * (v + 0.044715f * v * v * v);
  float t2 = __expf(2.f * u);
  float th = 1.f - 2.f / (t2 + 1.f);
  return 0.5f * v * (1.f + th);
}

// bijective XCD chunking (m204): XCD k owns logical ids [k*q, (k+1)*q)
__device__ __forceinline__ int xcd_swz(int orig, int nwg) {
  int xcd = orig & 7;
  int q = nwg >> 3, r = nwg & 7;
  int base = (xcd < r) ? xcd * (q + 1) : r * (q + 1) + (xcd - r) * q;
  return base + (orig >> 3);
}

// ---- 128x128 f32->bf16 transpose tile, 256 threads (R22-verified) ----
__device__ void wtrans128(char* __restrict__ ldsb,
                          const float* __restrict__ in, u16* __restrict__ out,
                          int M, int N, int r0, int c0)
{
  const int tid = threadIdx.x;
  #pragma unroll
  for (int p = 0; p < 16; p++) {
    int r  = p * 8 + (tid >> 5);
    int c4 = (tid & 31) * 4;
    float4 v = *(const float4*)(in + (size_t)(r0 + r) * N + (c0 + c4));
    ushort4 o;
    o.x = f2bf(v.x); o.y = f2bf(v.y); o.z = f2bf(v.z); o.w = f2bf(v.w);
    *(ushort4*)(ldsb + r * 272 + (r >> 3) * 16 + c4 * 2) = o;
  }
  __syncthreads();
  #pragma unroll
  for (int p = 0; p < 8; p++) {
    int idx = p * 256 + tid;
    int c   = idx >> 4;
    int rg  = idx & 15;
    short8 o;
    #pragma unroll
    for (int j = 0; j < 8; j++) {
      int r = rg * 8 + j;
      o[j] = *(const short*)(ldsb + r * 272 + rg * 16 + c * 2);
    }
    __builtin_nontemporal_store(*(u32x4*)&o,
        (u32x4*)(out + (size_t)(c0 + c) * M + (r0 + rg * 8)));
  }
}

// ---- same tile, 1024-thread variant (for fusion into gemm1's dispatch) ----
__device__ void wtrans128_w(char* __restrict__ ldsb,
                            const float* __restrict__ in, u16* __restrict__ out,
                            int M, int N, int r0, int c0)
{
  const int tid = threadIdx.x;
  #pragma unroll
  for (int p = 0; p < 4; p++) {
    int r  = p * 32 + (tid >> 5);
    int c4 = (tid & 31) * 4;
    float4 v = *(const float4*)(in + (size_t)(r0 + r) * N + (c0 + c4));
    ushort4 o;
    o.x = f2bf(v.x); o.y = f2bf(v.y); o.z = f2bf(v.z); o.w = f2bf(v.w);
    *(ushort4*)(ldsb + r * 272 + (r >> 3) * 16 + c4 * 2) = o;
  }
  __syncthreads();
  #pragma unroll
  for (int p = 0; p < 2; p++) {
    int idx = p * 1024 + tid;
    int c   = idx >> 4;
    int rg  = idx & 15;
    short8 o;
    #pragma unroll
    for (int j = 0; j < 8; j++) {
      int r = rg * 8 + j;
      o[j] = *(const short*)(ldsb + r * 272 + rg * 16 + c * 2);
    }
    __builtin_nontemporal_store(*(u32x4*)&o,
        (u32x4*)(out + (size_t)(c0 + c) * M + (r0 + rg * 8)));
  }
}

// ------- prep: W1-trans (blocks 0..2047) || router+xb (blocks 2048..4095) ----
__global__ __launch_bounds__(256) void prep_kernel(
    const float* __restrict__ x, const float* __restrict__ gw,
    const float* __restrict__ gb, u16* __restrict__ xb,
    int* __restrict__ counts, int* __restrict__ sel, float* __restrict__ wts,
    const float* __restrict__ w1, u16* __restrict__ w1t)
{
  __shared__ __align__(16) char ldsb[35072];
  const int b = blockIdx.x;
  if (b < 2048) {                         // W1: [DDIM][FDIM] -> [FDIM][DDIM]
    int e = b >> 8, rem = b & 255;        // 8 tm x 32 tn per expert
    int tm = rem & 7, tn = rem >> 3;
    wtrans128(ldsb, w1 + (size_t)e * DDIM * FDIM,
              w1t + (size_t)e * DDIM * FDIM, DDIM, FDIM, tm * 128, tn * 128);
    return;
  }
  // ---- router blocks ----
  float* gwT = (float*)ldsb;              // [8][1028] padded
  {
    const int tid = threadIdx.x;          // stage gw [1024][8] -> gwT[e][d]
    #pragma unroll
    for (int q = 0; q < 4; q++) {
      int d = q * 256 + tid;
      float4 a = *(const float4*)(gw + (size_t)d * NEXP);
      float4 cc = *(const float4*)(gw + (size_t)d * NEXP + 4);
      gwT[0 * 1028 + d] = a.x; gwT[1 * 1028 + d] = a.y;
      gwT[2 * 1028 + d] = a.z; gwT[3 * 1028 + d] = a.w;
      gwT[4 * 1028 + d] = cc.x; gwT[5 * 1028 + d] = cc.y;
      gwT[6 * 1028 + d] = cc.z; gwT[7 * 1028 + d] = cc.w;
    }
  }
  __syncthreads();
  const int t    = (b - 2048) * 4 + (threadIdx.x >> 6);
  const int lane = threadIdx.x & 63;
  const float* xr = x + (size_t)t * DDIM;
  u16* xbr = xb + (size_t)t * DDIM;
  float lg[NEXP];
  #pragma unroll
  for (int e = 0; e < NEXP; e++) lg[e] = 0.f;
  #pragma unroll
  for (int i = 0; i < 4; i++) {
    int d0 = i * 256 + lane * 4;
    float4 v = *(const float4*)(xr + d0);
    ushort4 o;
    o.x = f2bf(v.x); o.y = f2bf(v.y); o.z = f2bf(v.z); o.w = f2bf(v.w);
    *(ushort4*)(xbr + d0) = o;
    #pragma unroll
    for (int e = 0; e < NEXP; e++) {
      float4 g4 = *(const float4*)&gwT[e * 1028 + d0];
      lg[e] += v.x * g4.x + v.y * g4.y + v.z * g4.z + v.w * g4.w;
    }
  }
  #pragma unroll
  for (int off = 32; off > 0; off >>= 1) {
    #pragma unroll
    for (int e = 0; e < NEXP; e++) lg[e] += __shfl_down(lg[e], off);
  }
  if (lane == 0) {
    float v0 = -1e30f, v1 = -1e30f; int s0 = 0, s1 = 0;
    #pragma unroll
    for (int e = 0; e < NEXP; e++) {
      float v = lg[e] + gb[e];
      if (v > v0) { v1 = v0; s1 = s0; v0 = v; s0 = e; }
      else if (v > v1) { v1 = v; s1 = e; }
    }
    float a  = expf(v1 - v0);
    float w0 = 1.f / (1.f + a);
    sel[t * 2] = s0; sel[t * 2 + 1] = s1;
    wts[t * 2] = w0; wts[t * 2 + 1] = 1.f - w0;
    atomicAdd(&counts[s0], 1); atomicAdd(&counts[s1], 1);
  }
}

// ---------------- scan + tile map (256-row tiles) + slot assignment ----------
__global__ __launch_bounds__(1024) void scan_assign_kernel(
    const int* __restrict__ counts, const int* __restrict__ sel,
    const float* __restrict__ wts,
    int* __restrict__ offsets, int* __restrict__ map_e, int* __restrict__ map_r,
    int* __restrict__ nT, int* __restrict__ stok, float* __restrict__ swgt)
{
  __shared__ int spos[NEXP];
  if (threadIdx.x == 0) {
    int run = 0, nt = 0;
    for (int e = 0; e < NEXP; e++) {
      offsets[e] = run; spos[e] = run;
      int c = counts[e];
      int ntile = (c + 255) >> 8;
      for (int i = 0; i < ntile; i++) { map_e[nt] = e; map_r[nt] = i * 256; nt++; }
      run += c;
    }
    nT[0] = nt;
  }
  __syncthreads();
  for (int t = threadIdx.x; t < T_TOK; t += 1024) {
    #pragma unroll
    for (int k = 0; k < 2; k++) {
      int e = sel[t * 2 + k];
      int p = atomicAdd(&spos[e], 1);
      stok[p] = t; swgt[p] = wts[t * 2 + k];
    }
  }
}

// ---------------- grouped GEMM1 (+ fused W2-transpose blocks) ----------------
// Blocks 0..NG1-1: R15-proven 256x256 BK=32 16-wave ring-3 core.
// Blocks NG1..NG1+NW2T-1: W2 [FDIM][DDIM] -> w2t [DDIM][FDIM] transpose,
// hidden under gemm1's compute (w2t needed only by gemm2; stream-ordered).
__global__ __launch_bounds__(1024, 4) void gemm1_kernel(
    const u16* __restrict__ xb, const int* __restrict__ slot_token,
    const u16* __restrict__ W1T, const float* __restrict__ B1,
    const int* __restrict__ counts, const int* __restrict__ offsets,
    const int* __restrict__ map_e, const int* __restrict__ map_r,
    const int* __restrict__ nT, u16* __restrict__ H,
    const float* __restrict__ w2, u16* __restrict__ w2t)
{
  __shared__ __align__(16) char lds[3 * 32768]; // slot: [A 16KB | B 16KB]
  if (blockIdx.x >= NG1) {                 // W2 transpose block
    int b = blockIdx.x - NG1;              // 0..2047
    int e = b >> 8, rem = b & 255;         // 32 tm x 8 tn per expert
    int tm = rem >> 3, tn = rem & 7;
    wtrans128_w(lds, w2 + (size_t)e * FDIM * DDIM,
                w2t + (size_t)e * FDIM * DDIM, FDIM, DDIM, tm * 128, tn * 128);
    return;
  }
  const int L     = xcd_swz(blockIdx.x, NG1);
  const int xg    = L / 144;               // XCD 0..7
  const int local = L - xg * 144;
  const int tl    = local >> 4;            // 0..8 (9 t-tiles per XCD)
  const int n_idx = local & 15;            // n innermost: A reuse in L2
  const int t_idx = xg * 9 + tl;
  if (t_idx >= nT[0]) return;
  const int e    = map_e[t_idx];
  const int row0 = map_r[t_idx];
  const int cnt  = counts[e];
  const int off  = offsets[e];
  const int n0   = n_idx * 256;

  const int tid = threadIdx.x, wave = tid >> 6, lane = tid & 63;
  const int lr = lane & 15, lq = lane >> 4;
  const int wr = wave >> 2, wc = wave & 3;  // 4M x 4N
  const int l2 = lane >> 2, lb = (lane & 3) * 16;

  const int R = wave * 16 + l2;
  int tok = slot_token[imin(off + row0 + R, NSLOT - 1)];
  if ((u32)tok >= T_TOK) tok = 0;
  const char* gA = (const char*)xb + (size_t)tok * 2048 + lb;
  const char* gB = (const char*)W1T + (size_t)(e * FDIM + n0 + R) * 2048 + lb;

  auto stage = [&](int slot, int k0) {
    char* base = lds + slot * 32768;
    gload16(gA + k0, base + wave * 1024 + lane * 16);
    gload16(gB + k0, base + 16384 + wave * 1024 + lane * 16);
  };

  f32x4 acc[4][4] = {};
  auto compute = [&](int slot) {
    const u16* As = (const u16*)(lds + slot * 32768);
    const u16* Bs = (const u16*)(lds + slot * 32768 + 16384);
    short8 a[4], bf[4];
    #pragma unroll
    for (int m = 0; m < 4; m++)
      a[m] = *(const short8*)&As[(wr * 64 + m * 16 + lr) * 32 + lq * 8];
    #pragma unroll
    for (int n = 0; n < 4; n++)
      bf[n] = *(const short8*)&Bs[(wc * 64 + n * 16 + lr) * 32 + lq * 8];
    #pragma unroll
    for (int m = 0; m < 4; m++)
      #pragma unroll
      for (int n = 0; n < 4; n++)
        acc[m][n] = __builtin_amdgcn_mfma_f32_16x16x32_bf16(a[m], bf[n], acc[m][n], 0, 0, 0);
  };

  // NT = 32 K-steps (K=1024, BK=32; 64B per step). Ring-3, lead-2.
  stage(0, 0); stage(1, 64);
  VM2; SCHED0; SBAR; SCHED0;
  #pragma unroll 1
  for (int t = 0; t < 32; t++) {
    if (t + 2 < 32) stage((t + 2) % 3, (t + 2) * 64);
    compute(t % 3);
    SCHED0;
    if (t + 2 < 32)       { VM2; }
    else if (t + 2 == 32) { VM0; }
    SCHED0; SBAR; SCHED0;
  }

  // epilogue: gelu + bias + bf16 store
  #pragma unroll
  for (int nn = 0; nn < 4; nn++) {
    int col = n0 + wc * 64 + nn * 16 + lr;
    float b1v = B1[e * FDIM + col];
    #pragma unroll
    for (int m = 0; m < 4; m++) {
      int rbase = wr * 64 + m * 16 + lq * 4;
      #pragma unroll
      for (int j = 0; j < 4; j++) {
        int r = rbase + j;
        if (row0 + r < cnt) {
          float v = acc[m][nn][j] + b1v;
          H[(size_t)(off + row0 + r) * FDIM + col] = f2bf(gelu_fast(v));
        }
      }
    }
  }
}

// ---------------- grouped GEMM2 + fused combine ----------------
// R15-proven core; split-K=2 (NT=64 each). t-sliced decode: H rows re-read
// on the XCD that wrote them. out[tok] += wgt*(H@W2 + b2) via f32 atomics.
__global__ __launch_bounds__(1024, 4) void gemm2_kernel(
    const u16* __restrict__ H, const u16* __restrict__ W2T,
    const float* __restrict__ B2,
    const int* __restrict__ counts, const int* __restrict__ offsets,
    const int* __restrict__ slot_token, const float* __restrict__ slot_weight,
    const int* __restrict__ map_e, const int* __restrict__ map_r,
    const int* __restrict__ nT, float* __restrict__ out)
{
  __shared__ __align__(16) char lds[3 * 32768];
  const int L     = xcd_swz(blockIdx.x, NG2);
  const int xg    = L / 72;
  const int local = L - xg * 72;
  const int tl    = local >> 3;            // 0..8
  const int combo = local & 7;             // combo innermost: A reuse in L2
  const int sp    = combo >> 2;            // split-K half
  const int n_idx = combo & 3;             // 4 n-panels of 256
  const int t_idx = xg * 9 + tl;
  if (t_idx >= nT[0]) return;
  const int e    = map_e[t_idx];
  const int row0 = map_r[t_idx];
  const int cnt  = counts[e];
  const int off  = offsets[e];
  const int n0   = n_idx * 256;
  const int kbase = sp * 4096;             // bytes: elems [sp*2048, +2048)

  const int tid = threadIdx.x, wave = tid >> 6, lane = tid & 63;
  const int lr = lane & 15, lq = lane >> 4;
  const int wr = wave >> 2, wc = wave & 3;  // 4M x 4N
  const int l2 = lane >> 2, lb = (lane & 3) * 16;

  const int R = wave * 16 + l2;
  int aidx = imin(off + row0 + R, NSLOT - 1);
  const char* gA = (const char*)H + (size_t)aidx * 8192 + kbase + lb;
  const char* gB = (const char*)W2T + (size_t)(e * DDIM + n0 + R) * 8192 + kbase + lb;

  auto stage = [&](int slot, int k0) {
    char* base = lds + slot * 32768;
    gload16(gA + k0, base + wave * 1024 + lane * 16);
    gload16(gB + k0, base + 16384 + wave * 1024 + lane * 16);
  };

  f32x4 acc[4][4] = {};
  auto compute = [&](int slot) {
    const u16* As = (const u16*)(lds + slot * 32768);
    const u16* Bs = (const u16*)(lds + slot * 32768 + 16384);
    short8 a[4], bf[4];
    #pragma unroll
    for (int m = 0; m < 4; m++)
      a[m] = *(const short8*)&As[(wr * 64 + m * 16 + lr) * 32 + lq * 8];
    #pragma unroll
    for (int n = 0; n < 4; n++)
      bf[n] = *(const short8*)&Bs[(wc * 64 + n * 16 + lr) * 32 + lq * 8];
    #pragma unroll
    for (int m = 0; m < 4; m++)
      #pragma unroll
      for (int n = 0; n < 4; n++)
        acc[m][n] = __builtin_amdgcn_mfma_f32_16x16x32_bf16(a[m], bf[n], acc[m][n], 0, 0, 0);
  };

  // NT = 64 K-steps (split K=2048, BK=32). Ring-3, lead-2.
  stage(0, 0); stage(1, 64);
  VM2; SCHED0; SBAR; SCHED0;
  #pragma unroll 1
  for (int t = 0; t < 64; t++) {
    if (t + 2 < 64) stage((t + 2) % 3, (t + 2) * 64);
    compute(t % 3);
    SCHED0;
    if (t + 2 < 64)       { VM2; }
    else if (t + 2 == 64) { VM0; }
    SCHED0; SBAR; SCHED0;
  }

  #pragma unroll
  for (int m = 0; m < 4; m++) {
    int rbase = wr * 64 + m * 16 + lq * 4;
    #pragma unroll
    for (int j = 0; j < 4; j++) {
      int r = rbase + j;
      if (row0 + r >= cnt) continue;
      int s = off + row0 + r;
      int tok = slot_token[s];
      float wgt = slot_weight[s];
      #pragma unroll
      for (int n = 0; n < 4; n++) {
        int col = n0 + wc * 64 + n * 16 + lr;
        float v = acc[m][n][j];
        if (sp == 0) v += B2[e * DDIM + col];
        atomicAdd(&out[(size_t)tok * DDIM + col], wgt * v);
      }
    }
  }
}

extern "C" void kernel_launch(void* const* d_in, const int* in_sizes, int n_in,
                              void* d_out, int out_size, void* d_ws, size_t ws_size,
                              hipStream_t stream)
{
  (void)in_sizes; (void)n_in; (void)ws_size;
  const float* x  = (const float*)d_in[0];
  const float* gw = (const float*)d_in[1];
  const float* gb = (const float*)d_in[2];
  const float* w1 = (const float*)d_in[3];
  const float* b1 = (const float*)d_in[4];
  const float* w2 = (const float*)d_in[5];
  const float* b2 = (const float*)d_in[6];

  char* ws = (char*)d_ws;
  int*   counts = (int*)(ws + 0);
  int*   offp   = (int*)(ws + 64);
  int*   nT     = (int*)(ws + 128);
  int*   map_e  = (int*)(ws + 256);
  int*   map_r  = (int*)(ws + 1024);

  size_t p = 2048;
  int*   sel   = (int*)(ws + p);   p += (size_t)T_TOK * 2 * 4;
  float* wts   = (float*)(ws + p); p += (size_t)T_TOK * 2 * 4;
  int*   stok  = (int*)(ws + p);   p += (size_t)NSLOT * 4;
  float* swgt  = (float*)(ws + p); p += (size_t)NSLOT * 4;
  p = (p + 1048575) & ~(size_t)1048575;
  u16*   xb    = (u16*)(ws + p);   p += (size_t)T_TOK * DDIM * 2;
  u16*   w1t   = (u16*)(ws + p);   p += (size_t)NEXP * DDIM * FDIM * 2;
  u16*   w2t   = (u16*)(ws + p);   p += (size_t)NEXP * DDIM * FDIM * 2;
  u16*   Hbuf  = (u16*)(ws + p);   // (NSLOT + 256) rows x FDIM bf16

  hipMemsetAsync(ws, 0, 256, stream);
  hipMemsetAsync(d_out, 0, (size_t)out_size * sizeof(float), stream);
  prep_kernel<<<2048 + T_TOK / 4, 256, 0, stream>>>(
      x, gw, gb, xb, counts, sel, wts, w1, w1t);
  scan_assign_kernel<<<1, 1024, 0, stream>>>(counts, sel, wts, offp, map_e, map_r, nT, stok, swgt);
  gemm1_kernel<<<NG1 + NW2T, 1024, 0, stream>>>(
      xb, stok, w1t, b1, counts, offp, map_e, map_r, nT, Hbuf, w2, w2t);
  gemm2_kernel<<<NG2, 1024, 0, stream>>>(
      Hbuf, w2t, b2, counts, offp, stok, swgt, map_e, map_r, nT, (float*)d_out);
}